// Round 4
// baseline (558.316 us; speedup 1.0000x reference)
//
#include <hip/hip_runtime.h>

#define DIM 64
#define BSHIFT 8                 // bucket = dst >> 8  (node range 256/bucket)
#define MAXNB 1024               // max coarse buckets (N <= 262144)

// ---------------------------------------------------------------------------
// bf16 helpers (OCP bf16 = top 16 bits of fp32, RNE)
// ---------------------------------------------------------------------------
__device__ inline unsigned packbf(float a, float b) {
    unsigned ua = __float_as_uint(a), ub = __float_as_uint(b);
    unsigned ra = (ua + 0x7FFFu + ((ua >> 16) & 1u)) >> 16;
    unsigned rb = (ub + 0x7FFFu + ((ub >> 16) & 1u)) >> 16;
    return ra | (rb << 16);
}
__device__ inline void unpackbf(unsigned u, float& lo, float& hi) {
    lo = __uint_as_float(u << 16);
    hi = __uint_as_float(u & 0xFFFF0000u);
}
// accumulate 8 bf16 (one uint4) into s[0..7]
__device__ inline void acc_row(const uint4 v, float* s) {
    float lo, hi;
    unpackbf(v.x, lo, hi); s[0] += lo; s[1] += hi;
    unpackbf(v.y, lo, hi); s[2] += lo; s[3] += hi;
    unpackbf(v.z, lo, hi); s[4] += lo; s[5] += hi;
    unpackbf(v.w, lo, hi); s[6] += lo; s[7] += hi;
}

// ---------------------------------------------------------------------------
// Phase A: coarse histogram of dst>>BSHIFT (LDS-aggregated)
// ---------------------------------------------------------------------------
__global__ void coarse_hist_kernel(const int* __restrict__ col,
                                   int* __restrict__ bcnt, int E, int NB) {
    __shared__ int h[MAXNB];
    for (int i = threadIdx.x; i < NB; i += 256) h[i] = 0;
    __syncthreads();
    int e = blockIdx.x * 256 + threadIdx.x;
    int stride = gridDim.x * 256;
    for (; e < E; e += stride) atomicAdd(&h[col[e] >> BSHIFT], 1);
    __syncthreads();
    for (int i = threadIdx.x; i < NB; i += 256) {
        int v = h[i];
        if (v) atomicAdd(&bcnt[i], v);
    }
}

// ---------------------------------------------------------------------------
// Phase B: exclusive scan of bucket counts (single block, NB <= 1024)
// writes bbase[0..NB] and bcursor (= bbase copy)
// ---------------------------------------------------------------------------
__global__ void bucket_scan_kernel(const int* __restrict__ bcnt,
                                   int* __restrict__ bbase,
                                   int* __restrict__ bcursor, int NB, int E) {
    __shared__ int lds[256];
    int tid = threadIdx.x;
    int base = tid * 4;
    int c[4];
    int local = 0;
    #pragma unroll
    for (int k = 0; k < 4; k++) {
        c[k] = (base + k < NB) ? bcnt[base + k] : 0;
        local += c[k];
    }
    lds[tid] = local;
    __syncthreads();
    for (int off = 1; off < 256; off <<= 1) {
        int t = (tid >= off) ? lds[tid - off] : 0;
        __syncthreads();
        lds[tid] += t;
        __syncthreads();
    }
    int excl = lds[tid] - local;
    #pragma unroll
    for (int k = 0; k < 4; k++) {
        if (base + k < NB) {
            bbase[base + k] = excl;
            bcursor[base + k] = excl;
        }
        excl += c[k];
    }
    if (tid == 0) bbase[NB] = E;
}

// ---------------------------------------------------------------------------
// Phase C: coarse scatter into bucket-ordered pairs.
// pairs[pos] = src | (dst_local << 24)   (src < 2^24, dst_local < 256)
// Only NB active write streams, each sequential -> L2-hot tails.
// ---------------------------------------------------------------------------
__global__ void coarse_scatter_kernel(const int* __restrict__ row,
                                      const int* __restrict__ col,
                                      int* __restrict__ bcursor,
                                      unsigned* __restrict__ pairs, int E) {
    int e = blockIdx.x * 256 + threadIdx.x;
    if (e >= E) return;
    int d = col[e];
    int s = row[e];
    int b = d >> BSHIFT;
    int pos = atomicAdd(&bcursor[b], 1);
    pairs[pos] = (unsigned)s | ((unsigned)(d & 255) << 24);
}

// ---------------------------------------------------------------------------
// Phase D: fine fill — one workgroup per bucket; counts/scan/cursors in LDS;
// csr_src writes land in the bucket's contiguous (L2-resident) region.
// Also produces row_ptr (degree = row_ptr diff, so no separate cnt array).
// ---------------------------------------------------------------------------
__global__ void fine_fill_kernel(const unsigned* __restrict__ pairs,
                                 const int* __restrict__ bbase,
                                 int* __restrict__ row_ptr,
                                 int* __restrict__ csr_src, int N, int E) {
    __shared__ int cnt[256];
    __shared__ int cur[256];
    int b = blockIdx.x;
    int tid = threadIdx.x;
    int beg = bbase[b], end = bbase[b + 1];
    cnt[tid] = 0;
    __syncthreads();
    for (int j = beg + tid; j < end; j += 256)
        atomicAdd(&cnt[pairs[j] >> 24], 1);
    __syncthreads();
    int v = cnt[tid];
    for (int off = 1; off < 256; off <<= 1) {
        int t = (tid >= off) ? cnt[tid - off] : 0;
        __syncthreads();
        cnt[tid] += t;
        __syncthreads();
    }
    int excl = cnt[tid] - v;          // exclusive local prefix
    int node = (b << BSHIFT) + tid;
    if (node < N) row_ptr[node] = beg + excl;
    cur[tid] = beg + excl;
    __syncthreads();
    for (int j = beg + tid; j < end; j += 256) {
        unsigned p = pairs[j];
        int pos = atomicAdd(&cur[p >> 24], 1);
        csr_src[pos] = (int)(p & 0xFFFFFFu);
    }
    if (b == 0 && tid == 0) row_ptr[N] = E;
}

// ---------------------------------------------------------------------------
// prescale: z0 = deg^{-1/2} * emb, stored bf16.  8-lane group per node;
// lane loads 2 float4 (32 B fp32), writes 1 uint4 (8 bf16).
// ---------------------------------------------------------------------------
__global__ void prescale_kernel(const float4* __restrict__ emb4,
                                const int* __restrict__ row_ptr,
                                uint4* __restrict__ z4, int N) {
    int t = blockIdx.x * blockDim.x + threadIdx.x;
    int i = t >> 3;
    int gl = t & 7;
    if (i >= N) return;
    int deg = row_ptr[i + 1] - row_ptr[i];
    float wd = (deg > 0) ? rsqrtf((float)deg) : 0.0f;
    size_t eo = (size_t)i * 16 + gl * 2;
    float4 a = emb4[eo], b = emb4[eo + 1];
    uint4 z;
    z.x = packbf(a.x * wd, a.y * wd);
    z.y = packbf(a.z * wd, a.w * wd);
    z.z = packbf(b.x * wd, b.y * wd);
    z.w = packbf(b.z * wd, b.w * wd);
    z4[(size_t)i * 8 + gl] = z;
}

// ---------------------------------------------------------------------------
// pull SpMM on bf16 z:  t_i = sum z[src];  z_next[i] = t_i / deg
// 8-lane group per dst node (lane = uint4 = 8 bf16); 4-way edge unroll
// -> 32 independent 128 B gathers in flight per wave.
// ---------------------------------------------------------------------------
__global__ void spmm_pull_kernel(const int* __restrict__ row_ptr,
                                 const int* __restrict__ csr_src,
                                 const uint4* __restrict__ z4,
                                 uint4* __restrict__ znext4, int N) {
    int t = blockIdx.x * blockDim.x + threadIdx.x;
    int i = t >> 3;
    int gl = t & 7;
    if (i >= N) return;
    int b = row_ptr[i], e = row_ptr[i + 1];
    float s[8] = {0, 0, 0, 0, 0, 0, 0, 0};
    int j = b;
    for (; j + 3 < e; j += 4) {
        int i0 = csr_src[j], i1 = csr_src[j + 1];
        int i2 = csr_src[j + 2], i3 = csr_src[j + 3];
        uint4 v0 = z4[(size_t)i0 * 8 + gl];
        uint4 v1 = z4[(size_t)i1 * 8 + gl];
        uint4 v2 = z4[(size_t)i2 * 8 + gl];
        uint4 v3 = z4[(size_t)i3 * 8 + gl];
        acc_row(v0, s); acc_row(v1, s); acc_row(v2, s); acc_row(v3, s);
    }
    for (; j < e; ++j) {
        uint4 v = z4[(size_t)csr_src[j] * 8 + gl];
        acc_row(v, s);
    }
    int deg = e - b;
    float wd = (deg > 0) ? rsqrtf((float)deg) : 0.0f;
    float w2 = wd * wd;  // z_next = wd^2 * t
    uint4 z;
    z.x = packbf(s[0] * w2, s[1] * w2);
    z.y = packbf(s[2] * w2, s[3] * w2);
    z.z = packbf(s[4] * w2, s[5] * w2);
    z.w = packbf(s[6] * w2, s[7] * w2);
    znext4[(size_t)i * 8 + gl] = z;
}

// ---------------------------------------------------------------------------
// combine: acc = emb + sqrt(deg) * (z1 + z2 + z3), stored bf16
// (x_k = z_k / dis = sqrt(deg) * z_k; alpha applied at scoring)
// ---------------------------------------------------------------------------
__global__ void combine_kernel(const float4* __restrict__ emb4,
                               const uint4* __restrict__ z1,
                               const uint4* __restrict__ z2,
                               const uint4* __restrict__ z3,
                               const int* __restrict__ row_ptr,
                               uint4* __restrict__ accb, int N) {
    int t = blockIdx.x * blockDim.x + threadIdx.x;
    int i = t >> 3;
    int gl = t & 7;
    if (i >= N) return;
    int deg = row_ptr[i + 1] - row_ptr[i];
    float sq = sqrtf((float)deg);
    size_t zo = (size_t)i * 8 + gl;
    uint4 a = z1[zo], b = z2[zo], c = z3[zo];
    float s[8] = {0, 0, 0, 0, 0, 0, 0, 0};
    acc_row(a, s); acc_row(b, s); acc_row(c, s);
    size_t eo = (size_t)i * 16 + gl * 2;
    float4 e0 = emb4[eo], e1 = emb4[eo + 1];
    float r0 = e0.x + sq * s[0], r1 = e0.y + sq * s[1];
    float r2 = e0.z + sq * s[2], r3 = e0.w + sq * s[3];
    float r4 = e1.x + sq * s[4], r5 = e1.y + sq * s[5];
    float r6 = e1.z + sq * s[6], r7 = e1.w + sq * s[7];
    uint4 z;
    z.x = packbf(r0, r1);
    z.y = packbf(r2, r3);
    z.z = packbf(r4, r5);
    z.w = packbf(r6, r7);
    accb[zo] = z;
}

// ---------------------------------------------------------------------------
// logits[p] = alpha^2 * dot(acc[u], acc[i]) ; 8-lane group per pair (bf16 rows)
// ---------------------------------------------------------------------------
__global__ void score_kernel(const int* __restrict__ batch,
                             const uint4* __restrict__ accb,
                             float* __restrict__ out, int P) {
    int t = blockIdx.x * blockDim.x + threadIdx.x;
    int p = t >> 3;
    int gl = t & 7;
    if (p >= P) return;
    int u = batch[(size_t)p * 3 + 0];
    int it = batch[(size_t)p * 3 + 1];
    uint4 a = accb[(size_t)u * 8 + gl];
    uint4 b = accb[(size_t)it * 8 + gl];
    float sa[8] = {0, 0, 0, 0, 0, 0, 0, 0};
    float sb[8] = {0, 0, 0, 0, 0, 0, 0, 0};
    acc_row(a, sa);
    acc_row(b, sb);
    float s = sa[0] * sb[0] + sa[1] * sb[1] + sa[2] * sb[2] + sa[3] * sb[3] +
              sa[4] * sb[4] + sa[5] * sb[5] + sa[6] * sb[6] + sa[7] * sb[7];
    s += __shfl_xor(s, 4, 64);  // xor masks < 8 stay within the 8-lane group
    s += __shfl_xor(s, 2, 64);
    s += __shfl_xor(s, 1, 64);
    if (gl == 0) out[p] = s * 0.0625f;  // alpha^2, alpha = 1/(K_LAYERS+1)
}

extern "C" void kernel_launch(void* const* d_in, const int* in_sizes, int n_in,
                              void* d_out, int out_size, void* d_ws,
                              size_t ws_size, hipStream_t stream) {
    const float* emb = (const float*)d_in[0];
    const int* edge_index = (const int*)d_in[1];
    const int* batch = (const int*)d_in[2];
    float* out = (float*)d_out;

    const int N = in_sizes[0] / DIM;   // 200000
    const int E = in_sizes[1] / 2;     // 1250000
    const int P = out_size;            // 4096 * 101
    const int NB = (N + 255) >> BSHIFT;  // 782 coarse buckets

    const int* row = edge_index;       // sources
    const int* col = edge_index + E;   // targets

    const size_t zbytes = (size_t)N * DIM * 2;  // bf16 row buffer (25.6 MB)

    // workspace layout (~139 MB), 256 B aligned chunks
    auto align256 = [](size_t x) { return (x + 255) & ~(size_t)255; };
    char* ws = (char*)d_ws;
    uint4* z0   = (uint4*)ws; ws += align256(zbytes);
    uint4* z1   = (uint4*)ws; ws += align256(zbytes);
    uint4* z2   = (uint4*)ws; ws += align256(zbytes);
    uint4* z3   = (uint4*)ws; ws += align256(zbytes);
    uint4* accb = (uint4*)ws; ws += align256(zbytes);
    unsigned* pairs = (unsigned*)ws; ws += align256((size_t)E * 4);
    int* csr_src    = (int*)ws;      ws += align256((size_t)E * 4);
    int* row_ptr    = (int*)ws;      ws += align256((size_t)(N + 1) * 4);
    int* bcnt       = (int*)ws;      ws += align256((size_t)MAXNB * 4);
    int* bbase      = (int*)ws;      ws += align256((size_t)(MAXNB + 1) * 4);
    int* bcursor    = (int*)ws;

    // --- CSR build: coarse hist -> scan -> coarse scatter -> fine fill ---
    hipMemsetAsync(bcnt, 0, (size_t)MAXNB * 4, stream);
    coarse_hist_kernel<<<1024, 256, 0, stream>>>(col, bcnt, E, NB);
    bucket_scan_kernel<<<1, 256, 0, stream>>>(bcnt, bbase, bcursor, NB, E);
    coarse_scatter_kernel<<<(E + 255) / 256, 256, 0, stream>>>(row, col,
                                                               bcursor, pairs, E);
    fine_fill_kernel<<<NB, 256, 0, stream>>>(pairs, bbase, row_ptr, csr_src,
                                             N, E);

    const int nodeBlocks = (N * 8 + 255) / 256;  // 8-lane group per node

    // z0 = dis * emb  (bf16)
    prescale_kernel<<<nodeBlocks, 256, 0, stream>>>((const float4*)emb,
                                                    row_ptr, z0, N);

    // --- 3 pull-SpMM layers on bf16 z ---
    spmm_pull_kernel<<<nodeBlocks, 256, 0, stream>>>(row_ptr, csr_src, z0, z1, N);
    spmm_pull_kernel<<<nodeBlocks, 256, 0, stream>>>(row_ptr, csr_src, z1, z2, N);
    spmm_pull_kernel<<<nodeBlocks, 256, 0, stream>>>(row_ptr, csr_src, z2, z3, N);

    // acc = emb + sqrt(deg) * (z1 + z2 + z3)  (bf16)
    combine_kernel<<<nodeBlocks, 256, 0, stream>>>((const float4*)emb, z1, z2,
                                                   z3, row_ptr, accb, N);

    // --- scoring ---
    score_kernel<<<(P * 8 + 255) / 256, 256, 0, stream>>>(batch, accb, out, P);
}

// Round 5
// 271.339 us; speedup vs baseline: 2.0576x; 2.0576x over previous
//
#include <hip/hip_runtime.h>

#define DIM 64
#define BSHIFT 8                 // bucket = dst >> 8  (node range 256/bucket)
#define MAXNB 1024               // max coarse buckets (N <= 262144)
#define CHUNK 4096               // edges staged per block in binned scatter

// ---------------------------------------------------------------------------
// bf16 helpers (OCP bf16 = top 16 bits of fp32, RNE)
// ---------------------------------------------------------------------------
__device__ inline unsigned packbf(float a, float b) {
    unsigned ua = __float_as_uint(a), ub = __float_as_uint(b);
    unsigned ra = (ua + 0x7FFFu + ((ua >> 16) & 1u)) >> 16;
    unsigned rb = (ub + 0x7FFFu + ((ub >> 16) & 1u)) >> 16;
    return ra | (rb << 16);
}
__device__ inline void unpackbf(unsigned u, float& lo, float& hi) {
    lo = __uint_as_float(u << 16);
    hi = __uint_as_float(u & 0xFFFF0000u);
}
// accumulate 8 bf16 (one uint4) into s[0..7]
__device__ inline void acc_row(const uint4 v, float* s) {
    float lo, hi;
    unpackbf(v.x, lo, hi); s[0] += lo; s[1] += hi;
    unpackbf(v.y, lo, hi); s[2] += lo; s[3] += hi;
    unpackbf(v.z, lo, hi); s[4] += lo; s[5] += hi;
    unpackbf(v.w, lo, hi); s[6] += lo; s[7] += hi;
}

// ---------------------------------------------------------------------------
// Phase A: coarse histogram of dst>>BSHIFT (LDS-aggregated)
// ---------------------------------------------------------------------------
__global__ void coarse_hist_kernel(const int* __restrict__ col,
                                   int* __restrict__ bcnt, int E, int NB) {
    __shared__ int h[MAXNB];
    for (int i = threadIdx.x; i < NB; i += 256) h[i] = 0;
    __syncthreads();
    int e = blockIdx.x * 256 + threadIdx.x;
    int stride = gridDim.x * 256;
    for (; e < E; e += stride) atomicAdd(&h[col[e] >> BSHIFT], 1);
    __syncthreads();
    for (int i = threadIdx.x; i < NB; i += 256) {
        int v = h[i];
        if (v) atomicAdd(&bcnt[i], v);
    }
}

// ---------------------------------------------------------------------------
// Phase B: exclusive scan of bucket counts (single block, NB <= 1024)
// writes bbase[0..NB] and bcursor (= bbase copy)
// ---------------------------------------------------------------------------
__global__ void bucket_scan_kernel(const int* __restrict__ bcnt,
                                   int* __restrict__ bbase,
                                   int* __restrict__ bcursor, int NB, int E) {
    __shared__ int lds[256];
    int tid = threadIdx.x;
    int base = tid * 4;
    int c[4];
    int local = 0;
    #pragma unroll
    for (int k = 0; k < 4; k++) {
        c[k] = (base + k < NB) ? bcnt[base + k] : 0;
        local += c[k];
    }
    lds[tid] = local;
    __syncthreads();
    for (int off = 1; off < 256; off <<= 1) {
        int t = (tid >= off) ? lds[tid - off] : 0;
        __syncthreads();
        lds[tid] += t;
        __syncthreads();
    }
    int excl = lds[tid] - local;
    #pragma unroll
    for (int k = 0; k < 4; k++) {
        if (base + k < NB) {
            bbase[base + k] = excl;
            bcursor[base + k] = excl;
        }
        excl += c[k];
    }
    if (tid == 0) bbase[NB] = E;
}

// ---------------------------------------------------------------------------
// Phase C: BLOCK-BINNED coarse scatter.
// Each block stages CHUNK edges in LDS sorted by bucket, reserves one global
// range per (block,bucket) with a single atomicAdd, then writes sequential
// runs. Atomics: E/CHUNK*NB ~ 240K (vs E=1.25M), write runs ~5 edges each.
// pairs[pos] = src | (dst_local << 24)
// ---------------------------------------------------------------------------
__global__ __launch_bounds__(256) void scatter_binned_kernel(
        const int* __restrict__ row, const int* __restrict__ col,
        int* __restrict__ bcursor, unsigned* __restrict__ pairs, int E,
        int NB) {
    __shared__ unsigned stage[CHUNK];
    __shared__ int gdst[CHUNK];
    __shared__ int hist[MAXNB];   // counts -> local cursor
    __shared__ int pfx[MAXNB];    // exclusive local prefix
    __shared__ int gbase[MAXNB];  // global reservation base (also scan scratch)
    int tid = threadIdx.x;
    int base = blockIdx.x * CHUNK;
    int nloc = min(CHUNK, E - base);

    for (int b = tid; b < NB; b += 256) hist[b] = 0;
    __syncthreads();

    // load (coalesced) + LDS count; keep edges in registers
    unsigned vals[CHUNK / 256];
    int keys[CHUNK / 256];
    #pragma unroll
    for (int k = 0; k < CHUNK / 256; k++) {
        int e = base + tid + k * 256;
        if (e < E) {
            int d = col[e];
            int s = row[e];
            keys[k] = d >> BSHIFT;
            vals[k] = (unsigned)s | ((unsigned)(d & 255) << 24);
            atomicAdd(&hist[keys[k]], 1);
        } else {
            keys[k] = -1;
        }
    }
    __syncthreads();

    // exclusive scan of hist[0..NB) -> pfx  (4 buckets/thread, scratch=gbase)
    int b0 = tid * 4;
    int c4[4];
    int loc = 0;
    #pragma unroll
    for (int k = 0; k < 4; k++) {
        c4[k] = (b0 + k < NB) ? hist[b0 + k] : 0;
        loc += c4[k];
    }
    gbase[tid] = loc;
    __syncthreads();
    for (int off = 1; off < 256; off <<= 1) {
        int t = (tid >= off) ? gbase[tid - off] : 0;
        __syncthreads();
        gbase[tid] += t;
        __syncthreads();
    }
    int excl = gbase[tid] - loc;
    #pragma unroll
    for (int k = 0; k < 4; k++) {
        if (b0 + k < NB) pfx[b0 + k] = excl;
        excl += c4[k];
    }
    __syncthreads();

    // reserve global ranges (one atomic per nonzero bucket) + init cursors
    for (int b = tid; b < NB; b += 256) {
        int c = hist[b];
        gbase[b] = (c > 0) ? atomicAdd(&bcursor[b], c) : 0;
        hist[b] = pfx[b];  // hist becomes local cursor
    }
    __syncthreads();

    // bin into LDS (bucket-sorted), record global destination per slot
    #pragma unroll
    for (int k = 0; k < CHUNK / 256; k++) {
        if (keys[k] >= 0) {
            int slot = atomicAdd(&hist[keys[k]], 1);
            stage[slot] = vals[k];
            gdst[slot] = gbase[keys[k]] + (slot - pfx[keys[k]]);
        }
    }
    __syncthreads();

    // write out: lane-consecutive slots -> sequential runs per bucket
    for (int s = tid; s < nloc; s += 256) pairs[gdst[s]] = stage[s];
}

// ---------------------------------------------------------------------------
// Phase D: fine fill — one workgroup per bucket; counts/scan/cursors in LDS;
// csr_src writes land in the bucket's contiguous (L2-resident) region.
// Also produces row_ptr (degree = row_ptr diff).
// ---------------------------------------------------------------------------
__global__ void fine_fill_kernel(const unsigned* __restrict__ pairs,
                                 const int* __restrict__ bbase,
                                 int* __restrict__ row_ptr,
                                 int* __restrict__ csr_src, int N, int E) {
    __shared__ int cnt[256];
    __shared__ int cur[256];
    int b = blockIdx.x;
    int tid = threadIdx.x;
    int beg = bbase[b], end = bbase[b + 1];
    cnt[tid] = 0;
    __syncthreads();
    for (int j = beg + tid; j < end; j += 256)
        atomicAdd(&cnt[pairs[j] >> 24], 1);
    __syncthreads();
    int v = cnt[tid];
    for (int off = 1; off < 256; off <<= 1) {
        int t = (tid >= off) ? cnt[tid - off] : 0;
        __syncthreads();
        cnt[tid] += t;
        __syncthreads();
    }
    int excl = cnt[tid] - v;          // exclusive local prefix
    int node = (b << BSHIFT) + tid;
    if (node < N) row_ptr[node] = beg + excl;
    cur[tid] = beg + excl;
    __syncthreads();
    for (int j = beg + tid; j < end; j += 256) {
        unsigned p = pairs[j];
        int pos = atomicAdd(&cur[p >> 24], 1);
        csr_src[pos] = (int)(p & 0xFFFFFFu);
    }
    if (b == 0 && tid == 0) row_ptr[N] = E;
}

// ---------------------------------------------------------------------------
// prescale: z0 = deg^{-1/2} * emb, stored bf16.  8-lane group per node
// ---------------------------------------------------------------------------
__global__ void prescale_kernel(const float4* __restrict__ emb4,
                                const int* __restrict__ row_ptr,
                                uint4* __restrict__ z4, int N) {
    int t = blockIdx.x * blockDim.x + threadIdx.x;
    int i = t >> 3;
    int gl = t & 7;
    if (i >= N) return;
    int deg = row_ptr[i + 1] - row_ptr[i];
    float wd = (deg > 0) ? rsqrtf((float)deg) : 0.0f;
    size_t eo = (size_t)i * 16 + gl * 2;
    float4 a = emb4[eo], b = emb4[eo + 1];
    uint4 z;
    z.x = packbf(a.x * wd, a.y * wd);
    z.y = packbf(a.z * wd, a.w * wd);
    z.z = packbf(b.x * wd, b.y * wd);
    z.w = packbf(b.z * wd, b.w * wd);
    z4[(size_t)i * 8 + gl] = z;
}

// ---------------------------------------------------------------------------
// pull SpMM on bf16 z:  t_i = sum z[src];  z_next[i] = t_i / deg
// 8-lane group per dst node; 4-way edge unroll -> 32 gathers in flight/wave
// ---------------------------------------------------------------------------
__global__ void spmm_pull_kernel(const int* __restrict__ row_ptr,
                                 const int* __restrict__ csr_src,
                                 const uint4* __restrict__ z4,
                                 uint4* __restrict__ znext4, int N) {
    int t = blockIdx.x * blockDim.x + threadIdx.x;
    int i = t >> 3;
    int gl = t & 7;
    if (i >= N) return;
    int b = row_ptr[i], e = row_ptr[i + 1];
    float s[8] = {0, 0, 0, 0, 0, 0, 0, 0};
    int j = b;
    for (; j + 3 < e; j += 4) {
        int i0 = csr_src[j], i1 = csr_src[j + 1];
        int i2 = csr_src[j + 2], i3 = csr_src[j + 3];
        uint4 v0 = z4[(size_t)i0 * 8 + gl];
        uint4 v1 = z4[(size_t)i1 * 8 + gl];
        uint4 v2 = z4[(size_t)i2 * 8 + gl];
        uint4 v3 = z4[(size_t)i3 * 8 + gl];
        acc_row(v0, s); acc_row(v1, s); acc_row(v2, s); acc_row(v3, s);
    }
    for (; j < e; ++j) {
        uint4 v = z4[(size_t)csr_src[j] * 8 + gl];
        acc_row(v, s);
    }
    int deg = e - b;
    float wd = (deg > 0) ? rsqrtf((float)deg) : 0.0f;
    float w2 = wd * wd;  // z_next = wd^2 * t
    uint4 z;
    z.x = packbf(s[0] * w2, s[1] * w2);
    z.y = packbf(s[2] * w2, s[3] * w2);
    z.z = packbf(s[4] * w2, s[5] * w2);
    z.w = packbf(s[6] * w2, s[7] * w2);
    znext4[(size_t)i * 8 + gl] = z;
}

// ---------------------------------------------------------------------------
// fused layer-3 SpMM + combine:
//   t = sum_{nbr} z2[src];  acc = emb + sqrt(deg)*(z1+z2) + wd*t   (bf16)
// (since sqrt(deg) * wd^2 = wd).  Saves materializing z3 entirely.
// ---------------------------------------------------------------------------
__global__ void spmm_combine_kernel(const int* __restrict__ row_ptr,
                                    const int* __restrict__ csr_src,
                                    const uint4* __restrict__ z2,
                                    const uint4* __restrict__ z1,
                                    const float4* __restrict__ emb4,
                                    uint4* __restrict__ accb, int N) {
    int t = blockIdx.x * blockDim.x + threadIdx.x;
    int i = t >> 3;
    int gl = t & 7;
    if (i >= N) return;
    int b = row_ptr[i], e = row_ptr[i + 1];
    float s[8] = {0, 0, 0, 0, 0, 0, 0, 0};
    int j = b;
    for (; j + 3 < e; j += 4) {
        int i0 = csr_src[j], i1 = csr_src[j + 1];
        int i2 = csr_src[j + 2], i3 = csr_src[j + 3];
        uint4 v0 = z2[(size_t)i0 * 8 + gl];
        uint4 v1 = z2[(size_t)i1 * 8 + gl];
        uint4 v2 = z2[(size_t)i2 * 8 + gl];
        uint4 v3 = z2[(size_t)i3 * 8 + gl];
        acc_row(v0, s); acc_row(v1, s); acc_row(v2, s); acc_row(v3, s);
    }
    for (; j < e; ++j) {
        uint4 v = z2[(size_t)csr_src[j] * 8 + gl];
        acc_row(v, s);
    }
    int deg = e - b;
    float wd = (deg > 0) ? rsqrtf((float)deg) : 0.0f;
    float sq = (deg > 0) ? sqrtf((float)deg) : 0.0f;
    // own-node z1+z2
    size_t zo = (size_t)i * 8 + gl;
    uint4 a1 = z1[zo], a2 = z2[zo];
    float w[8] = {0, 0, 0, 0, 0, 0, 0, 0};
    acc_row(a1, w); acc_row(a2, w);
    size_t eo = (size_t)i * 16 + gl * 2;
    float4 e0 = emb4[eo], e1 = emb4[eo + 1];
    float r0 = e0.x + sq * w[0] + wd * s[0];
    float r1 = e0.y + sq * w[1] + wd * s[1];
    float r2 = e0.z + sq * w[2] + wd * s[2];
    float r3 = e0.w + sq * w[3] + wd * s[3];
    float r4 = e1.x + sq * w[4] + wd * s[4];
    float r5 = e1.y + sq * w[5] + wd * s[5];
    float r6 = e1.z + sq * w[6] + wd * s[6];
    float r7 = e1.w + sq * w[7] + wd * s[7];
    uint4 z;
    z.x = packbf(r0, r1);
    z.y = packbf(r2, r3);
    z.z = packbf(r4, r5);
    z.w = packbf(r6, r7);
    accb[zo] = z;
}

// ---------------------------------------------------------------------------
// logits[p] = alpha^2 * dot(acc[u], acc[i]) ; 8-lane group per pair
// ---------------------------------------------------------------------------
__global__ void score_kernel(const int* __restrict__ batch,
                             const uint4* __restrict__ accb,
                             float* __restrict__ out, int P) {
    int t = blockIdx.x * blockDim.x + threadIdx.x;
    int p = t >> 3;
    int gl = t & 7;
    if (p >= P) return;
    int u = batch[(size_t)p * 3 + 0];
    int it = batch[(size_t)p * 3 + 1];
    uint4 a = accb[(size_t)u * 8 + gl];
    uint4 b = accb[(size_t)it * 8 + gl];
    float sa[8] = {0, 0, 0, 0, 0, 0, 0, 0};
    float sb[8] = {0, 0, 0, 0, 0, 0, 0, 0};
    acc_row(a, sa);
    acc_row(b, sb);
    float s = sa[0] * sb[0] + sa[1] * sb[1] + sa[2] * sb[2] + sa[3] * sb[3] +
              sa[4] * sb[4] + sa[5] * sb[5] + sa[6] * sb[6] + sa[7] * sb[7];
    s += __shfl_xor(s, 4, 64);  // xor masks < 8 stay within the 8-lane group
    s += __shfl_xor(s, 2, 64);
    s += __shfl_xor(s, 1, 64);
    if (gl == 0) out[p] = s * 0.0625f;  // alpha^2, alpha = 1/(K_LAYERS+1)
}

extern "C" void kernel_launch(void* const* d_in, const int* in_sizes, int n_in,
                              void* d_out, int out_size, void* d_ws,
                              size_t ws_size, hipStream_t stream) {
    const float* emb = (const float*)d_in[0];
    const int* edge_index = (const int*)d_in[1];
    const int* batch = (const int*)d_in[2];
    float* out = (float*)d_out;

    const int N = in_sizes[0] / DIM;   // 200000
    const int E = in_sizes[1] / 2;     // 1250000
    const int P = out_size;            // 4096 * 101
    const int NB = (N + 255) >> BSHIFT;  // 782 coarse buckets

    const int* row = edge_index;       // sources
    const int* col = edge_index + E;   // targets

    const size_t zbytes = (size_t)N * DIM * 2;  // bf16 row buffer (25.6 MB)

    // workspace layout (~113 MB), 256 B aligned chunks
    auto align256 = [](size_t x) { return (x + 255) & ~(size_t)255; };
    char* ws = (char*)d_ws;
    uint4* z0   = (uint4*)ws; ws += align256(zbytes);
    uint4* z1   = (uint4*)ws; ws += align256(zbytes);
    uint4* z2   = (uint4*)ws; ws += align256(zbytes);
    uint4* accb = (uint4*)ws; ws += align256(zbytes);
    unsigned* pairs = (unsigned*)ws; ws += align256((size_t)E * 4);
    int* csr_src    = (int*)ws;      ws += align256((size_t)E * 4);
    int* row_ptr    = (int*)ws;      ws += align256((size_t)(N + 1) * 4);
    int* bcnt       = (int*)ws;      ws += align256((size_t)MAXNB * 4);
    int* bbase      = (int*)ws;      ws += align256((size_t)(MAXNB + 1) * 4);
    int* bcursor    = (int*)ws;

    // --- CSR build: coarse hist -> scan -> binned scatter -> fine fill ---
    hipMemsetAsync(bcnt, 0, (size_t)MAXNB * 4, stream);
    coarse_hist_kernel<<<1024, 256, 0, stream>>>(col, bcnt, E, NB);
    bucket_scan_kernel<<<1, 256, 0, stream>>>(bcnt, bbase, bcursor, NB, E);
    scatter_binned_kernel<<<(E + CHUNK - 1) / CHUNK, 256, 0, stream>>>(
        row, col, bcursor, pairs, E, NB);
    fine_fill_kernel<<<NB, 256, 0, stream>>>(pairs, bbase, row_ptr, csr_src,
                                             N, E);

    const int nodeBlocks = (N * 8 + 255) / 256;  // 8-lane group per node

    // z0 = dis * emb  (bf16)
    prescale_kernel<<<nodeBlocks, 256, 0, stream>>>((const float4*)emb,
                                                    row_ptr, z0, N);

    // --- layers 1,2 pull-SpMM; layer 3 fused with combine ---
    spmm_pull_kernel<<<nodeBlocks, 256, 0, stream>>>(row_ptr, csr_src, z0, z1, N);
    spmm_pull_kernel<<<nodeBlocks, 256, 0, stream>>>(row_ptr, csr_src, z1, z2, N);
    spmm_combine_kernel<<<nodeBlocks, 256, 0, stream>>>(row_ptr, csr_src, z2,
                                                        z1, (const float4*)emb,
                                                        accb, N);

    // --- scoring ---
    score_kernel<<<(P * 8 + 255) / 256, 256, 0, stream>>>(batch, accb, out, P);
}

// Round 6
// 249.924 us; speedup vs baseline: 2.2339x; 1.0857x over previous
//
#include <hip/hip_runtime.h>

#define DIM 64
#define BSHIFT 8                 // bucket = dst >> 8  (node range 256/bucket)
#define MAXNB 1024               // max coarse buckets (N <= 262144)
#define CHUNK 4096               // edges per block in hist/scatter passes

// ---------------------------------------------------------------------------
// bf16 helpers (OCP bf16 = top 16 bits of fp32, RNE)
// ---------------------------------------------------------------------------
__device__ inline unsigned packbf(float a, float b) {
    unsigned ua = __float_as_uint(a), ub = __float_as_uint(b);
    unsigned ra = (ua + 0x7FFFu + ((ua >> 16) & 1u)) >> 16;
    unsigned rb = (ub + 0x7FFFu + ((ub >> 16) & 1u)) >> 16;
    return ra | (rb << 16);
}
__device__ inline void unpackbf(unsigned u, float& lo, float& hi) {
    lo = __uint_as_float(u << 16);
    hi = __uint_as_float(u & 0xFFFF0000u);
}
// s[0..7] += 8 bf16 (one uint4)
__device__ inline void acc_row(const uint4 v, float* s) {
    float lo, hi;
    unpackbf(v.x, lo, hi); s[0] += lo; s[1] += hi;
    unpackbf(v.y, lo, hi); s[2] += lo; s[3] += hi;
    unpackbf(v.z, lo, hi); s[4] += lo; s[5] += hi;
    unpackbf(v.w, lo, hi); s[6] += lo; s[7] += hi;
}
// s[0..7] += m * (8 bf16)   (m = 0/1 tail mask -> fma, no branch)
__device__ inline void acc_row_m(const uint4 v, float m, float* s) {
    float lo, hi;
    unpackbf(v.x, lo, hi); s[0] = fmaf(m, lo, s[0]); s[1] = fmaf(m, hi, s[1]);
    unpackbf(v.y, lo, hi); s[2] = fmaf(m, lo, s[2]); s[3] = fmaf(m, hi, s[3]);
    unpackbf(v.z, lo, hi); s[4] = fmaf(m, lo, s[4]); s[5] = fmaf(m, hi, s[5]);
    unpackbf(v.w, lo, hi); s[6] = fmaf(m, lo, s[6]); s[7] = fmaf(m, hi, s[7]);
}

// ---------------------------------------------------------------------------
// K1: per-block bucket histogram.  H[k*nblocks + b] = count of chunk-b edges
// with dst-bucket k.  (bucket-major so the global scan yields contiguous
// bucket ranges)
// ---------------------------------------------------------------------------
__global__ __launch_bounds__(256) void block_hist_kernel(
        const int* __restrict__ col, int* __restrict__ H, int E, int NB,
        int nblocks) {
    __shared__ int h[MAXNB];
    int tid = threadIdx.x;
    for (int k = tid; k < NB; k += 256) h[k] = 0;
    __syncthreads();
    int base = blockIdx.x * CHUNK;
    #pragma unroll
    for (int k = 0; k < CHUNK / 256; k++) {
        int e = base + tid + k * 256;
        if (e < E) atomicAdd(&h[col[e] >> BSHIFT], 1);
    }
    __syncthreads();
    for (int k = tid; k < NB; k += 256) H[(size_t)k * nblocks + blockIdx.x] = h[k];
}

// ---------------------------------------------------------------------------
// K2/K3/K4: 3-kernel exclusive scan of H[0..M) -> S ; T = tile sums (<=256)
// ---------------------------------------------------------------------------
__global__ void scan_tile_sum_kernel(const int* __restrict__ H,
                                     int* __restrict__ T, int M) {
    int tid = threadIdx.x;
    int base = blockIdx.x * 1024 + tid * 4;
    int s = 0;
    #pragma unroll
    for (int k = 0; k < 4; k++)
        if (base + k < M) s += H[base + k];
    __shared__ int lds[256];
    lds[tid] = s;
    __syncthreads();
    for (int off = 128; off > 0; off >>= 1) {
        if (tid < off) lds[tid] += lds[tid + off];
        __syncthreads();
    }
    if (tid == 0) T[blockIdx.x] = lds[0];
}

__global__ void scan_tile_offsets_kernel(int* __restrict__ T, int nt) {
    __shared__ int lds[256];
    int tid = threadIdx.x;
    int v = (tid < nt) ? T[tid] : 0;
    lds[tid] = v;
    __syncthreads();
    for (int off = 1; off < 256; off <<= 1) {
        int t = (tid >= off) ? lds[tid - off] : 0;
        __syncthreads();
        lds[tid] += t;
        __syncthreads();
    }
    if (tid < nt) T[tid] = lds[tid] - v;  // exclusive
}

__global__ void scan_final_kernel(const int* __restrict__ H,
                                  const int* __restrict__ T,
                                  int* __restrict__ S, int M) {
    int tid = threadIdx.x;
    int base = blockIdx.x * 1024 + tid * 4;
    int c[4];
    int local = 0;
    #pragma unroll
    for (int k = 0; k < 4; k++) {
        c[k] = (base + k < M) ? H[base + k] : 0;
        local += c[k];
    }
    __shared__ int lds[256];
    lds[tid] = local;
    __syncthreads();
    for (int off = 1; off < 256; off <<= 1) {
        int t = (tid >= off) ? lds[tid - off] : 0;
        __syncthreads();
        lds[tid] += t;
        __syncthreads();
    }
    int excl = lds[tid] - local + T[blockIdx.x];
    #pragma unroll
    for (int k = 0; k < 4; k++) {
        if (base + k < M) S[base + k] = excl;
        excl += c[k];
    }
}

// bbase[k] = S[k*nblocks] ; bbase[NB] = E
__global__ void bbase_kernel(const int* __restrict__ S, int* __restrict__ bbase,
                             int NB, int nblocks, int E) {
    int k = blockIdx.x * blockDim.x + threadIdx.x;
    if (k < NB) bbase[k] = S[(size_t)k * nblocks];
    if (k == 0) bbase[NB] = E;
}

// ---------------------------------------------------------------------------
// K5: deterministic binned scatter. Bases come from S — zero global atomics.
// pairs[pos] = src | (dst_local << 24)
// ---------------------------------------------------------------------------
__global__ __launch_bounds__(256) void scatter_binned_kernel(
        const int* __restrict__ row, const int* __restrict__ col,
        const int* __restrict__ S, unsigned* __restrict__ pairs, int E,
        int NB, int nblocks) {
    __shared__ unsigned stage[CHUNK];
    __shared__ int gdst[CHUNK];
    __shared__ int hist[MAXNB];   // counts -> local cursor
    __shared__ int pfx[MAXNB];    // exclusive local prefix
    __shared__ int gbase[MAXNB];  // per-(block,bucket) base (scan scratch too)
    int tid = threadIdx.x;
    int bid = blockIdx.x;
    int base = bid * CHUNK;
    int nloc = min(CHUNK, E - base);

    for (int b = tid; b < NB; b += 256) hist[b] = 0;
    __syncthreads();

    unsigned vals[CHUNK / 256];
    int keys[CHUNK / 256];
    #pragma unroll
    for (int k = 0; k < CHUNK / 256; k++) {
        int e = base + tid + k * 256;
        if (e < E) {
            int d = col[e];
            int s = row[e];
            keys[k] = d >> BSHIFT;
            vals[k] = (unsigned)s | ((unsigned)(d & 255) << 24);
            atomicAdd(&hist[keys[k]], 1);
        } else {
            keys[k] = -1;
        }
    }
    __syncthreads();

    // exclusive scan of hist -> pfx (4 buckets/thread; scratch = gbase)
    int b0 = tid * 4;
    int c4[4];
    int loc = 0;
    #pragma unroll
    for (int k = 0; k < 4; k++) {
        c4[k] = (b0 + k < NB) ? hist[b0 + k] : 0;
        loc += c4[k];
    }
    gbase[tid] = loc;
    __syncthreads();
    for (int off = 1; off < 256; off <<= 1) {
        int t = (tid >= off) ? gbase[tid - off] : 0;
        __syncthreads();
        gbase[tid] += t;
        __syncthreads();
    }
    int excl = gbase[tid] - loc;
    #pragma unroll
    for (int k = 0; k < 4; k++) {
        if (b0 + k < NB) pfx[b0 + k] = excl;
        excl += c4[k];
    }
    __syncthreads();

    // deterministic global bases + init local cursors
    for (int b = tid; b < NB; b += 256) {
        gbase[b] = S[(size_t)b * nblocks + bid];
        hist[b] = pfx[b];
    }
    __syncthreads();

    // bin into LDS (bucket-sorted)
    #pragma unroll
    for (int k = 0; k < CHUNK / 256; k++) {
        if (keys[k] >= 0) {
            int slot = atomicAdd(&hist[keys[k]], 1);
            stage[slot] = vals[k];
            gdst[slot] = gbase[keys[k]] + (slot - pfx[keys[k]]);
        }
    }
    __syncthreads();

    // sequential runs per bucket
    for (int s = tid; s < nloc; s += 256) pairs[gdst[s]] = stage[s];
}

// ---------------------------------------------------------------------------
// K6: fine fill — one workgroup per bucket; LDS count/scan/cursors;
// produces row_ptr (degree = diff) and dst-grouped csr_src.
// ---------------------------------------------------------------------------
__global__ void fine_fill_kernel(const unsigned* __restrict__ pairs,
                                 const int* __restrict__ bbase,
                                 int* __restrict__ row_ptr,
                                 int* __restrict__ csr_src, int N, int E) {
    __shared__ int cnt[256];
    __shared__ int cur[256];
    int b = blockIdx.x;
    int tid = threadIdx.x;
    int beg = bbase[b], end = bbase[b + 1];
    cnt[tid] = 0;
    __syncthreads();
    for (int j = beg + tid; j < end; j += 256)
        atomicAdd(&cnt[pairs[j] >> 24], 1);
    __syncthreads();
    int v = cnt[tid];
    for (int off = 1; off < 256; off <<= 1) {
        int t = (tid >= off) ? cnt[tid - off] : 0;
        __syncthreads();
        cnt[tid] += t;
        __syncthreads();
    }
    int excl = cnt[tid] - v;
    int node = (b << BSHIFT) + tid;
    if (node < N) row_ptr[node] = beg + excl;
    cur[tid] = beg + excl;
    __syncthreads();
    for (int j = beg + tid; j < end; j += 256) {
        unsigned p = pairs[j];
        int pos = atomicAdd(&cur[p >> 24], 1);
        csr_src[pos] = (int)(p & 0xFFFFFFu);
    }
    if (b == 0 && tid == 0) row_ptr[N] = E;
}

// ---------------------------------------------------------------------------
// prescale: z0 = deg^{-1/2} * emb, stored bf16.  8-lane group per node
// ---------------------------------------------------------------------------
__global__ void prescale_kernel(const float4* __restrict__ emb4,
                                const int* __restrict__ row_ptr,
                                uint4* __restrict__ z4, int N) {
    int t = blockIdx.x * blockDim.x + threadIdx.x;
    int i = t >> 3;
    int gl = t & 7;
    if (i >= N) return;
    int deg = row_ptr[i + 1] - row_ptr[i];
    float wd = (deg > 0) ? rsqrtf((float)deg) : 0.0f;
    size_t eo = (size_t)i * 16 + gl * 2;
    float4 a = emb4[eo], b = emb4[eo + 1];
    uint4 z;
    z.x = packbf(a.x * wd, a.y * wd);
    z.y = packbf(a.z * wd, a.w * wd);
    z.z = packbf(b.x * wd, b.y * wd);
    z.w = packbf(b.z * wd, b.w * wd);
    z4[(size_t)i * 8 + gl] = z;
}

// ---------------------------------------------------------------------------
// software-pipelined gather-sum over one CSR row (8-lane group):
// clamped-index quads (tail masked by fma), next quad's indices prefetched
// while current gathers are in flight.
// ---------------------------------------------------------------------------
__device__ inline void row_gather_sum(const int* __restrict__ csr_src,
                                      const uint4* __restrict__ z4, int b,
                                      int e, int gl, float* s) {
    if (b >= e) return;
    int e1 = e - 1;
    int j = b;
    int i0 = csr_src[j];
    int i1 = csr_src[min(j + 1, e1)];
    int i2 = csr_src[min(j + 2, e1)];
    int i3 = csr_src[min(j + 3, e1)];
    while (j < e) {
        uint4 v0 = z4[(size_t)i0 * 8 + gl];
        uint4 v1 = z4[(size_t)i1 * 8 + gl];
        uint4 v2 = z4[(size_t)i2 * 8 + gl];
        uint4 v3 = z4[(size_t)i3 * 8 + gl];
        int jn = j + 4;
        if (jn < e) {  // prefetch next quad (independent of gathers above)
            i0 = csr_src[jn];
            i1 = csr_src[min(jn + 1, e1)];
            i2 = csr_src[min(jn + 2, e1)];
            i3 = csr_src[min(jn + 3, e1)];
        }
        float m1 = (j + 1 < e) ? 1.0f : 0.0f;
        float m2 = (j + 2 < e) ? 1.0f : 0.0f;
        float m3 = (j + 3 < e) ? 1.0f : 0.0f;
        acc_row(v0, s);
        acc_row_m(v1, m1, s);
        acc_row_m(v2, m2, s);
        acc_row_m(v3, m3, s);
        j = jn;
    }
}

// ---------------------------------------------------------------------------
// pull SpMM on bf16 z:  z_next[i] = (sum z[src]) / deg
// ---------------------------------------------------------------------------
__global__ void spmm_pull_kernel(const int* __restrict__ row_ptr,
                                 const int* __restrict__ csr_src,
                                 const uint4* __restrict__ z4,
                                 uint4* __restrict__ znext4, int N) {
    int t = blockIdx.x * blockDim.x + threadIdx.x;
    int i = t >> 3;
    int gl = t & 7;
    if (i >= N) return;
    int b = row_ptr[i], e = row_ptr[i + 1];
    float s[8] = {0, 0, 0, 0, 0, 0, 0, 0};
    row_gather_sum(csr_src, z4, b, e, gl, s);
    int deg = e - b;
    float wd = (deg > 0) ? rsqrtf((float)deg) : 0.0f;
    float w2 = wd * wd;
    uint4 z;
    z.x = packbf(s[0] * w2, s[1] * w2);
    z.y = packbf(s[2] * w2, s[3] * w2);
    z.z = packbf(s[4] * w2, s[5] * w2);
    z.w = packbf(s[6] * w2, s[7] * w2);
    znext4[(size_t)i * 8 + gl] = z;
}

// ---------------------------------------------------------------------------
// fused layer-3 SpMM + combine:
//   t = sum_{nbr} z2[src];  acc = emb + sqrt(deg)*(z1+z2) + wd*t   (bf16)
// ---------------------------------------------------------------------------
__global__ void spmm_combine_kernel(const int* __restrict__ row_ptr,
                                    const int* __restrict__ csr_src,
                                    const uint4* __restrict__ z2,
                                    const uint4* __restrict__ z1,
                                    const float4* __restrict__ emb4,
                                    uint4* __restrict__ accb, int N) {
    int t = blockIdx.x * blockDim.x + threadIdx.x;
    int i = t >> 3;
    int gl = t & 7;
    if (i >= N) return;
    int b = row_ptr[i], e = row_ptr[i + 1];
    float s[8] = {0, 0, 0, 0, 0, 0, 0, 0};
    row_gather_sum(csr_src, z2, b, e, gl, s);
    int deg = e - b;
    float wd = (deg > 0) ? rsqrtf((float)deg) : 0.0f;
    float sq = (deg > 0) ? sqrtf((float)deg) : 0.0f;
    size_t zo = (size_t)i * 8 + gl;
    uint4 a1 = z1[zo], a2 = z2[zo];
    float w[8] = {0, 0, 0, 0, 0, 0, 0, 0};
    acc_row(a1, w); acc_row(a2, w);
    size_t eo = (size_t)i * 16 + gl * 2;
    float4 e0 = emb4[eo], e1 = emb4[eo + 1];
    float r0 = e0.x + sq * w[0] + wd * s[0];
    float r1 = e0.y + sq * w[1] + wd * s[1];
    float r2 = e0.z + sq * w[2] + wd * s[2];
    float r3 = e0.w + sq * w[3] + wd * s[3];
    float r4 = e1.x + sq * w[4] + wd * s[4];
    float r5 = e1.y + sq * w[5] + wd * s[5];
    float r6 = e1.z + sq * w[6] + wd * s[6];
    float r7 = e1.w + sq * w[7] + wd * s[7];
    uint4 z;
    z.x = packbf(r0, r1);
    z.y = packbf(r2, r3);
    z.z = packbf(r4, r5);
    z.w = packbf(r6, r7);
    accb[zo] = z;
}

// ---------------------------------------------------------------------------
// logits[p] = alpha^2 * dot(acc[u], acc[i]) ; 8-lane group per pair
// ---------------------------------------------------------------------------
__global__ void score_kernel(const int* __restrict__ batch,
                             const uint4* __restrict__ accb,
                             float* __restrict__ out, int P) {
    int t = blockIdx.x * blockDim.x + threadIdx.x;
    int p = t >> 3;
    int gl = t & 7;
    if (p >= P) return;
    int u = batch[(size_t)p * 3 + 0];
    int it = batch[(size_t)p * 3 + 1];
    uint4 a = accb[(size_t)u * 8 + gl];
    uint4 b = accb[(size_t)it * 8 + gl];
    float sa[8] = {0, 0, 0, 0, 0, 0, 0, 0};
    float sb[8] = {0, 0, 0, 0, 0, 0, 0, 0};
    acc_row(a, sa);
    acc_row(b, sb);
    float s = sa[0] * sb[0] + sa[1] * sb[1] + sa[2] * sb[2] + sa[3] * sb[3] +
              sa[4] * sb[4] + sa[5] * sb[5] + sa[6] * sb[6] + sa[7] * sb[7];
    s += __shfl_xor(s, 4, 64);
    s += __shfl_xor(s, 2, 64);
    s += __shfl_xor(s, 1, 64);
    if (gl == 0) out[p] = s * 0.0625f;  // alpha^2, alpha = 1/(K_LAYERS+1)
}

extern "C" void kernel_launch(void* const* d_in, const int* in_sizes, int n_in,
                              void* d_out, int out_size, void* d_ws,
                              size_t ws_size, hipStream_t stream) {
    const float* emb = (const float*)d_in[0];
    const int* edge_index = (const int*)d_in[1];
    const int* batch = (const int*)d_in[2];
    float* out = (float*)d_out;

    const int N = in_sizes[0] / DIM;        // 200000
    const int E = in_sizes[1] / 2;          // 1250000
    const int P = out_size;                 // 4096 * 101
    const int NB = (N + 255) >> BSHIFT;     // 782 coarse buckets
    const int nblocks = (E + CHUNK - 1) / CHUNK;  // 306 edge chunks
    const int M = NB * nblocks;             // 239292 scan entries
    const int nt = (M + 1023) / 1024;       // 234 scan tiles (<=256)

    const int* row = edge_index;            // sources
    const int* col = edge_index + E;        // targets

    const size_t zbytes = (size_t)N * DIM * 2;  // bf16 row buffer (25.6 MB)

    auto align256 = [](size_t x) { return (x + 255) & ~(size_t)255; };
    char* ws = (char*)d_ws;
    uint4* z0   = (uint4*)ws; ws += align256(zbytes);
    uint4* z1   = (uint4*)ws; ws += align256(zbytes);
    uint4* z2   = (uint4*)ws; ws += align256(zbytes);
    uint4* accb = (uint4*)ws; ws += align256(zbytes);
    unsigned* pairs = (unsigned*)ws; ws += align256((size_t)E * 4);
    int* csr_src    = (int*)ws;      ws += align256((size_t)E * 4);
    int* row_ptr    = (int*)ws;      ws += align256((size_t)(N + 1) * 4);
    int* H          = (int*)ws;      ws += align256((size_t)M * 4);
    int* S          = (int*)ws;      ws += align256((size_t)M * 4);
    int* T          = (int*)ws;      ws += align256(256 * 4);
    int* bbase      = (int*)ws;

    // --- deterministic radix CSR build (no memsets, no global atomics) ---
    block_hist_kernel<<<nblocks, 256, 0, stream>>>(col, H, E, NB, nblocks);
    scan_tile_sum_kernel<<<nt, 256, 0, stream>>>(H, T, M);
    scan_tile_offsets_kernel<<<1, 256, 0, stream>>>(T, nt);
    scan_final_kernel<<<nt, 256, 0, stream>>>(H, T, S, M);
    bbase_kernel<<<(NB + 255) / 256, 256, 0, stream>>>(S, bbase, NB, nblocks, E);
    scatter_binned_kernel<<<nblocks, 256, 0, stream>>>(row, col, S, pairs, E,
                                                       NB, nblocks);
    fine_fill_kernel<<<NB, 256, 0, stream>>>(pairs, bbase, row_ptr, csr_src,
                                             N, E);

    const int nodeBlocks = (N * 8 + 255) / 256;  // 8-lane group per node

    // z0 = deg^{-1/2} * emb  (bf16)
    prescale_kernel<<<nodeBlocks, 256, 0, stream>>>((const float4*)emb,
                                                    row_ptr, z0, N);

    // --- layers 1,2 pull-SpMM; layer 3 fused with combine ---
    spmm_pull_kernel<<<nodeBlocks, 256, 0, stream>>>(row_ptr, csr_src, z0, z1, N);
    spmm_pull_kernel<<<nodeBlocks, 256, 0, stream>>>(row_ptr, csr_src, z1, z2, N);
    spmm_combine_kernel<<<nodeBlocks, 256, 0, stream>>>(row_ptr, csr_src, z2,
                                                        z1, (const float4*)emb,
                                                        accb, N);

    // --- scoring ---
    score_kernel<<<(P * 8 + 255) / 256, 256, 0, stream>>>(batch, accb, out, P);
}